// Round 2
// baseline (638.230 us; speedup 1.0000x reference)
//
#include <hip/hip_runtime.h>
#include <math.h>

namespace {

constexpr int N_ = 8, C_ = 256, S_ = 64, HW_ = 256;
constexpr int NS = N_ * S_;      // 512 columns (n,s)
constexpr int NHW = N_ * HW_;    // 2048 columns (n,hw)

// ---- workspace layout (float offsets) ----
constexpr size_t O_DESC  = 0;            // [512][256]
constexpr size_t O_DN    = 131072;
constexpr size_t O_MOT   = 393216;
constexpr size_t O_GATE  = 524288;
constexpr size_t O_MEM   = 786432;
constexpr size_t O_PHASE = 1048576;
constexpr size_t O_DELTA = 1441792;
constexpr size_t O_SCN   = 1572864;      // [512][512] scan out: fwd c<256, bwd c>=256
constexpr size_t O_SPT   = 2752512;      // [2048][256]
constexpr size_t O_SGATE = 3276800;      // [2048][256]
constexpr size_t O_FE    = 3801088;      // 264 used
constexpr size_t O_MFRE  = 3801600;
constexpr size_t O_MFIM  = 3802112;
constexpr size_t O_BW    = 3802656;      // [n][3]
constexpr size_t O_ATMF  = 3802688;
constexpr size_t O_ATMG  = 3868224;
constexpr size_t O_ATMO1 = 3999296;
constexpr size_t O_ATMO2 = 4195904;
constexpr size_t O_ATPP  = 4261440;
constexpr size_t O_ATBP1 = 4326976;
constexpr size_t O_ATBP2 = 4589120;
constexpr size_t O_ATFG  = 4654656;
constexpr size_t O_ATSG  = 4720192;
constexpr size_t O_WFRAG = 4785728;      // bf16 [168 kchunk][48 m16][64 lane][8]
constexpr size_t O_IM2   = 6850112;      // bf16 [168 kchunk][32 c16][64 lane][8]
constexpr size_t O_CONVC = 8226368;      // fp32 [4 kp][768][512]

typedef __attribute__((ext_vector_type(4))) float f32x4;
typedef __attribute__((ext_vector_type(8))) short s16x8;
typedef __attribute__((ext_vector_type(8))) unsigned short u16x8;

__device__ __forceinline__ float gelu_f(float v) {
  return 0.5f * v * (1.0f + erff(v * 0.70710678118654752f));
}
__device__ __forceinline__ float sigmoid_f(float v) {
  return 1.0f / (1.0f + expf(-v));
}
__device__ __forceinline__ unsigned short f2bf(float f) {
  unsigned int u = __float_as_uint(f);
  u += 0x7fffu + ((u >> 16) & 1u);
  return (unsigned short)(u >> 16);
}

// block (256 threads) sum with broadcast; scratch = 4 floats in LDS
__device__ __forceinline__ float block_sum256(float v, float* scratch) {
  #pragma unroll
  for (int off = 32; off; off >>= 1) v += __shfl_down(v, off, 64);
  int w = threadIdx.x >> 6;
  __syncthreads();
  if ((threadIdx.x & 63) == 0) scratch[w] = v;
  __syncthreads();
  return scratch[0] + scratch[1] + scratch[2] + scratch[3];
}

// peak params per n (26-element serial scan, uniform loads — bit-identical in all callers)
__device__ __forceinline__ void compute_pk(
    int n, const float* __restrict__ fe, const float* __restrict__ mfre,
    const float* __restrict__ mfim,
    float& conf, float& pnorm, float& dph, float& ang) {
  const float* f = fe + n * 33;
  float best = f[7]; int bidx = 0; float hs = 0.f;
  #pragma unroll
  for (int i = 0; i < 26; ++i) {
    float v = f[7 + i];
    hs += v;
    if (v > best) { best = v; bidx = i; }
  }
  int pi = bidx + 7;
  conf = best / fmaxf(hs, 1e-6f);
  pnorm = (float)pi * (1.f / 32.f);
  dph = atan2f(mfim[n * 33 + pi], mfre[n * 33 + pi]);
  ang = (6.283185307179586f / 64.f) * (float)pi;
}

// ---------------- weight prep: 1x1 transpose + conv A-fragment pack, one launch ----------------
__global__ __launch_bounds__(256) void weights_kernel(
    const float* __restrict__ wmf, const float* __restrict__ wmg,
    const float* __restrict__ wmo1, const float* __restrict__ wmo2,
    const float* __restrict__ wpp, const float* __restrict__ wbp1,
    const float* __restrict__ wbp2, const float* __restrict__ wfg,
    const float* __restrict__ wsg, float* __restrict__ ws,
    const float* __restrict__ w3, const float* __restrict__ w5,
    const float* __restrict__ w7, unsigned short* __restrict__ wf) {
  int bid = blockIdx.x;
  if (bid < 960) {
    __shared__ float tile[32][33];
    int xt = bid % 120, yt = bid / 120;
    const float* src; float* dst; int K;
    if      (xt < 8)   { src = wmf;  dst = ws + O_ATMF;  K = 256;  }
    else if (xt < 24)  { src = wmg;  dst = ws + O_ATMG;  K = 512;  xt -= 8;  }
    else if (xt < 48)  { src = wmo1; dst = ws + O_ATMO1; K = 768;  xt -= 24; }
    else if (xt < 56)  { src = wmo2; dst = ws + O_ATMO2; K = 256;  xt -= 48; }
    else if (xt < 64)  { src = wpp;  dst = ws + O_ATPP;  K = 256;  xt -= 56; }
    else if (xt < 96)  { src = wbp1; dst = ws + O_ATBP1; K = 1024; xt -= 64; }
    else if (xt < 104) { src = wbp2; dst = ws + O_ATBP2; K = 256;  xt -= 96; }
    else if (xt < 112) { src = wfg;  dst = ws + O_ATFG;  K = 256;  xt -= 104;}
    else               { src = wsg;  dst = ws + O_ATSG;  K = 256;  xt -= 112;}
    int tx = threadIdx.x & 31, ty = threadIdx.x >> 5;
    int c = xt * 32 + tx;
    #pragma unroll
    for (int i = 0; i < 4; ++i) {
      int r = yt * 32 + ty + i * 8;
      tile[ty + i * 8][tx] = src[(size_t)r * K + c];
    }
    __syncthreads();
    #pragma unroll
    for (int i = 0; i < 4; ++i) {
      int cc = xt * 32 + ty + i * 8;
      dst[(size_t)cc * 256 + yt * 32 + tx] = tile[tx][ty + i * 8];
    }
  } else {
    int g = (bid - 960) * 256 + threadIdx.x;       // one lane-slot
    int lane = g & 63;
    int m16 = (g >> 6) % 48;
    int kchunk = (g >> 6) / 48;
    int o = m16 * 16 + (lane & 15);
    int conv = o >> 8, oc = o & 255;
    int q = lane >> 4;
    u16x8 outv;
    #pragma unroll
    for (int j = 0; j < 8; ++j) {
      int k = kchunk * 32 + q * 8 + j;
      int ic = k / 7;
      int tau = k - ic * 7 - 3;
      float v = 0.f;
      if (conv == 0) {
        if (tau >= -1 && tau <= 1) v = w3[((size_t)oc * 768 + ic) * 3 + (tau + 1)];
      } else if (conv == 1) {
        if (tau >= -2 && tau <= 2) v = w5[((size_t)oc * 768 + ic) * 5 + (tau + 2)];
      } else {
        v = w7[((size_t)oc * 768 + ic) * 7 + (tau + 3)];
      }
      outv[j] = f2bf(v);
    }
    *((u16x8*)wf + g) = outv;
  }
}

// ---------------- pass 1: x reductions ----------------
__global__ __launch_bounds__(256) void reduce_x_kernel(
    const float* __restrict__ x, float* __restrict__ desc_t, float* __restrict__ sp_t) {
  int nc = blockIdx.x; int n = nc >> 8; int c = nc & 255;
  int t = threadIdx.x; int w = t >> 6; int l = t & 63;
  const float4* x4 = (const float4*)x + (size_t)nc * 4096;
  float4 sa = {0.f, 0.f, 0.f, 0.f};
  for (int i = 0; i < 16; ++i) {
    int s = w * 16 + i;
    float4 v = x4[(size_t)s * 64 + l];
    sa.x += v.x; sa.y += v.y; sa.z += v.z; sa.w += v.w;
    float ds = v.x + v.y + v.z + v.w;
    #pragma unroll
    for (int off = 32; off; off >>= 1) ds += __shfl_down(ds, off, 64);
    if (l == 0) desc_t[((size_t)n * 64 + s) * 256 + c] = ds * (1.f / 256.f);
  }
  __shared__ float4 lsp[4][64];
  lsp[w][l] = sa;
  __syncthreads();
  if (t < 64) {
    float4 a = lsp[0][t], b = lsp[1][t], c2 = lsp[2][t], d = lsp[3][t];
    float4 tot;
    tot.x = a.x + b.x + c2.x + d.x; tot.y = a.y + b.y + c2.y + d.y;
    tot.z = a.z + b.z + c2.z + d.z; tot.w = a.w + b.w + c2.w + d.w;
    size_t base = ((size_t)n * 256 + t * 4) * 256 + c;
    sp_t[base]       = tot.x * (1.f / 64.f);
    sp_t[base + 256] = tot.y * (1.f / 64.f);
    sp_t[base + 512] = tot.z * (1.f / 64.f);
    sp_t[base + 768] = tot.w * (1.f / 64.f);
  }
}

// ---------------- LayerNorm over C per (n,s) ----------------
__global__ __launch_bounds__(256) void ln_kernel(
    const float* __restrict__ desc_t, const float* __restrict__ g,
    const float* __restrict__ b, float* __restrict__ dn_t) {
  __shared__ float sc[4];
  int col = blockIdx.x; int t = threadIdx.x;
  float v = desc_t[(size_t)col * 256 + t];
  float s1 = block_sum256(v, sc);
  float s2 = block_sum256(v * v, sc);
  float mu = s1 * (1.f / 256.f);
  float var = s2 * (1.f / 256.f) - mu * mu;
  float r = rsqrtf(var + 1e-5f);
  dn_t[(size_t)col * 256 + t] = (v - mu) * r * g[t] + b[t];
}

// ---------------- mega: gate C4 (128) + im2col (1344) + fft (264) ----------------
__global__ __launch_bounds__(256) void post_ln_kernel(
    const float* __restrict__ dn_t, const float* __restrict__ At_mg,
    const float* __restrict__ mg_b, float* __restrict__ gate_t,
    unsigned short* __restrict__ imf,
    float* __restrict__ fe, float* __restrict__ mfre, float* __restrict__ mfim) {
  __shared__ __align__(16) float smem[2048];
  int bid = blockIdx.x;
  int t = threadIdx.x;
  if (bid < 128) {
    // ---- gate, 4 cols/block ----
    int c0 = bid * 4;
    float4 f0, f1;
    {
      float d[4], a[4];
      #pragma unroll
      for (int i = 0; i < 4; ++i) {
        int col = c0 + i; int s = col & 63;
        float dd = dn_t[(size_t)col * 256 + t];
        float d1 = (s >= 1) ? dd - dn_t[(size_t)(col - 1) * 256 + t] : 0.f;
        d[i] = dd; a[i] = fabsf(d1);
      }
      f0.x = d[0]; f0.y = d[1]; f0.z = d[2]; f0.w = d[3];
      f1.x = a[0]; f1.y = a[1]; f1.z = a[2]; f1.w = a[3];
    }
    *(float4*)&smem[t * 4] = f0;
    *(float4*)&smem[(256 + t) * 4] = f1;
    __syncthreads();
    float a0 = 0.f, a1 = 0.f, a2 = 0.f, a3 = 0.f;
    #pragma unroll 4
    for (int k = 0; k < 512; ++k) {
      float a = At_mg[(size_t)k * 256 + t];
      float4 b = *(const float4*)&smem[k * 4];
      a0 += a * b.x; a1 += a * b.y; a2 += a * b.z; a3 += a * b.w;
    }
    float bb = mg_b[t];
    gate_t[(size_t)(c0 + 0) * 256 + t] = sigmoid_f(a0 + bb);
    gate_t[(size_t)(c0 + 1) * 256 + t] = sigmoid_f(a1 + bb);
    gate_t[(size_t)(c0 + 2) * 256 + t] = sigmoid_f(a2 + bb);
    gate_t[(size_t)(c0 + 3) * 256 + t] = sigmoid_f(a3 + bb);
  } else if (bid < 1472) {
    // ---- im2col B-fragments ----
    int g = (bid - 128) * 256 + t;
    int lane = g & 63;
    int c16 = (g >> 6) % 32;
    int kchunk = (g >> 6) / 32;
    int col = c16 * 16 + (lane & 15);
    int n = col >> 6, s = col & 63;
    int q = lane >> 4;
    const float* base = dn_t + (size_t)n * 16384;
    u16x8 outv;
    #pragma unroll
    for (int j = 0; j < 8; ++j) {
      int k = kchunk * 32 + q * 8 + j;
      int ic = k / 7;
      int tau = k - ic * 7 - 3;
      int stream = ic >> 8, c = ic & 255;
      int sp = s + tau;
      float v = 0.f;
      if (sp >= 0 && sp < 64) {
        float d = base[(size_t)sp * 256 + c];
        if (stream == 0) v = d;
        else if (stream == 1) v = (sp >= 1) ? d - base[(size_t)(sp - 1) * 256 + c] : 0.f;
        else v = (sp >= 2) ? d - base[(size_t)(sp - 2) * 256 + c] : 0.f;
      }
      outv[j] = f2bf(v);
    }
    *((u16x8*)imf + g) = outv;
  } else {
    // ---- rFFT (direct DFT) ----
    int b = bid - 1472; int n = b / 33; int f = b % 33;
    float* cs = smem; float* sn = smem + 64; float* scr = smem + 128;
    if (t < 64) {
      int ft = (f * t) & 63;
      float ang = -6.283185307179586f * (float)ft * (1.f / 64.f);
      cs[t] = cosf(ang); sn[t] = sinf(ang);
    }
    __syncthreads();
    float re = 0.f, im = 0.f;
    const float* base = dn_t + (size_t)n * 16384 + t;
    for (int s = 0; s < 64; ++s) {
      float v = base[(size_t)s * 256];
      re += v * cs[s]; im += v * sn[s];
    }
    re *= 0.125f; im *= 0.125f;   // ortho 1/sqrt(64)
    float mag = sqrtf(re * re + im * im);
    float sm = block_sum256(mag, scr);
    float sr = block_sum256(re, scr);
    float si = block_sum256(im, scr);
    if (t == 0) {
      fe[b]   = sm * (1.f / 256.f);
      mfre[b] = sr * (1.f / 256.f);
      mfim[b] = si * (1.f / 256.f);
    }
  }
}

// ---------------- mega: conv MFMA (384) + gated scan (16) ----------------
__global__ __launch_bounds__(256) void conv_scan_kernel(
    const unsigned short* __restrict__ wf, const unsigned short* __restrict__ imf,
    float* __restrict__ partial,
    const float* __restrict__ dn_t, const float* __restrict__ gate_t,
    float* __restrict__ scn) {
  __shared__ float smem[16384];   // 64 KB, used by scan blocks only
  int bid = blockIdx.x;
  int t = threadIdx.x;
  if (bid < 384) {
    int mt = bid % 12; int rem = bid / 12;
    int nt = rem % 8; int kp = rem / 8;
    int lane = t & 63;
    int w = t >> 6;
    int m16 = mt * 4 + w;
    const s16x8* wfp = (const s16x8*)wf;
    const s16x8* imp = (const s16x8*)imf;
    f32x4 acc0 = {0.f,0.f,0.f,0.f}, acc1 = {0.f,0.f,0.f,0.f};
    f32x4 acc2 = {0.f,0.f,0.f,0.f}, acc3 = {0.f,0.f,0.f,0.f};
    #pragma unroll 2
    for (int cc = 0; cc < 42; ++cc) {
      int kc = kp * 42 + cc;
      s16x8 a = wfp[(size_t)(kc * 48 + m16) * 64 + lane];
      s16x8 b0 = imp[(size_t)(kc * 32 + nt * 4 + 0) * 64 + lane];
      s16x8 b1 = imp[(size_t)(kc * 32 + nt * 4 + 1) * 64 + lane];
      s16x8 b2 = imp[(size_t)(kc * 32 + nt * 4 + 2) * 64 + lane];
      s16x8 b3 = imp[(size_t)(kc * 32 + nt * 4 + 3) * 64 + lane];
      acc0 = __builtin_amdgcn_mfma_f32_16x16x32_bf16(a, b0, acc0, 0, 0, 0);
      acc1 = __builtin_amdgcn_mfma_f32_16x16x32_bf16(a, b1, acc1, 0, 0, 0);
      acc2 = __builtin_amdgcn_mfma_f32_16x16x32_bf16(a, b2, acc2, 0, 0, 0);
      acc3 = __builtin_amdgcn_mfma_f32_16x16x32_bf16(a, b3, acc3, 0, 0, 0);
    }
    int q = lane >> 4, ln = lane & 15;
    int o0 = m16 * 16 + q * 4;
    float* pb = partial + (size_t)kp * 393216;
    #pragma unroll
    for (int r = 0; r < 4; ++r) {
      size_t row = (size_t)(o0 + r) * 512;
      pb[row + (nt * 4 + 0) * 16 + ln] = acc0[r];
      pb[row + (nt * 4 + 1) * 16 + ln] = acc1[r];
      pb[row + (nt * 4 + 2) * 16 + ln] = acc2[r];
      pb[row + (nt * 4 + 3) * 16 + ln] = acc3[r];
    }
  } else {
    int idx = bid - 384;
    int n = idx >> 1, half = idx & 1;
    float* ld = smem;
    float* lg = smem + 8192;
    const float* dsrc = dn_t + (size_t)n * 16384 + half * 128;
    const float* gsrc = gate_t + (size_t)n * 16384 + half * 128;
    for (int i = t; i < 8192; i += 256) {
      int s = i >> 7, j = i & 127;
      ld[i] = dsrc[(size_t)s * 256 + j];
      lg[i] = gsrc[(size_t)s * 256 + j];
    }
    __syncthreads();
    int cl = t & 127;
    int c = half * 128 + cl;
    size_t ob = (size_t)n * 64 * 512 + c;
    if (t < 128) {
      float st = ld[cl];
      scn[ob] = st;
      for (int s = 1; s < 64; ++s) {
        float g = lg[s * 128 + cl], d = ld[s * 128 + cl];
        st = g * st + (1.f - g) * d;
        scn[ob + (size_t)s * 512] = st;
      }
    } else {
      float st = ld[63 * 128 + cl];
      scn[ob + (size_t)63 * 512 + 256] = st;
      for (int s = 62; s >= 0; --s) {
        float g = lg[s * 128 + cl], d = ld[s * 128 + cl];
        st = g * st + (1.f - g) * d;
        scn[ob + (size_t)s * 512 + 256] = st;
      }
    }
  }
}

// ---------------- mega: motion C4 (128) + memory C4 (128) + phase C4 (128) + sgate C4 (512) ----------------
__global__ __launch_bounds__(256) void mid_kernel(
    const float* __restrict__ P,
    const float* __restrict__ s3, const float* __restrict__ b3,
    const float* __restrict__ s5, const float* __restrict__ b5,
    const float* __restrict__ s7, const float* __restrict__ b7,
    const float* __restrict__ At_mf, const float* __restrict__ mf_s,
    const float* __restrict__ mf_b, float* __restrict__ motion_t,
    const float* __restrict__ dn_t, const float* __restrict__ scn,
    const float* __restrict__ At1, const float* __restrict__ sc1, const float* __restrict__ bi1,
    const float* __restrict__ At2, float* __restrict__ mem_t,
    const float* __restrict__ fe, const float* __restrict__ mfre, const float* __restrict__ mfim,
    const float* __restrict__ pg_w1, const float* __restrict__ pg_s1, const float* __restrict__ pg_b1,
    const float* __restrict__ pg_w2, const float* __restrict__ pg_b2,
    const float* __restrict__ At_pp, const float* __restrict__ pp_s, const float* __restrict__ pp_b,
    float* __restrict__ phase_t,
    const float* __restrict__ At_sg, const float* __restrict__ sp_t,
    const float* __restrict__ sg_s, const float* __restrict__ sg_b,
    float* __restrict__ sgate_t) {
  __shared__ __align__(16) float smem[4096];
  int bid = blockIdx.x;
  int t = threadIdx.x;
  if (bid < 128) {
    // ---- motion: combine conv partials + bn/gelu/avg + mf gemm ----
    int c0 = bid * 4;
    float4 v3 = {0,0,0,0}, v5 = {0,0,0,0}, v7 = {0,0,0,0};
    #pragma unroll
    for (int kp = 0; kp < 4; ++kp) {
      const float* base = P + (size_t)kp * 393216 + c0;
      float4 x3 = *(const float4*)(base + (size_t)t * 512);
      float4 x5 = *(const float4*)(base + (size_t)(t + 256) * 512);
      float4 x7 = *(const float4*)(base + (size_t)(t + 512) * 512);
      v3.x += x3.x; v3.y += x3.y; v3.z += x3.z; v3.w += x3.w;
      v5.x += x5.x; v5.y += x5.y; v5.z += x5.z; v5.w += x5.w;
      v7.x += x7.x; v7.y += x7.y; v7.z += x7.z; v7.w += x7.w;
    }
    float s3v = s3[t], b3v = b3[t], s5v = s5[t], b5v = b5[t], s7v = s7[t], b7v = b7[t];
    float4 ms;
    ms.x = (gelu_f(v3.x*s3v+b3v) + gelu_f(v5.x*s5v+b5v) + gelu_f(v7.x*s7v+b7v)) * (1.f/3.f);
    ms.y = (gelu_f(v3.y*s3v+b3v) + gelu_f(v5.y*s5v+b5v) + gelu_f(v7.y*s7v+b7v)) * (1.f/3.f);
    ms.z = (gelu_f(v3.z*s3v+b3v) + gelu_f(v5.z*s5v+b5v) + gelu_f(v7.z*s7v+b7v)) * (1.f/3.f);
    ms.w = (gelu_f(v3.w*s3v+b3v) + gelu_f(v5.w*s5v+b5v) + gelu_f(v7.w*s7v+b7v)) * (1.f/3.f);
    *(float4*)&smem[t * 4] = ms;
    __syncthreads();
    float a0 = 0.f, a1 = 0.f, a2 = 0.f, a3 = 0.f;
    #pragma unroll 4
    for (int k = 0; k < 256; ++k) {
      float a = At_mf[(size_t)k * 256 + t];
      float4 b = *(const float4*)&smem[k * 4];
      a0 += a * b.x; a1 += a * b.y; a2 += a * b.z; a3 += a * b.w;
    }
    float sv = mf_s[t], bv2 = mf_b[t];
    motion_t[(size_t)(c0 + 0) * 256 + t] = gelu_f(a0 * sv + bv2);
    motion_t[(size_t)(c0 + 1) * 256 + t] = gelu_f(a1 * sv + bv2);
    motion_t[(size_t)(c0 + 2) * 256 + t] = gelu_f(a2 * sv + bv2);
    motion_t[(size_t)(c0 + 3) * 256 + t] = gelu_f(a3 * sv + bv2);
  } else if (bid < 256) {
    // ---- memory: mo1 + mo2 ----
    int c0 = (bid - 128) * 4;
    float* bv = smem;          // [768][4]
    float* h4 = smem + 3072;   // [256][4]
    float4 r0, r1, r2;
    #pragma unroll
    for (int i = 0; i < 4; ++i) {
      int col = c0 + i;
      ((float*)&r0)[i] = dn_t[(size_t)col * 256 + t];
      ((float*)&r1)[i] = scn[(size_t)col * 512 + t];
      ((float*)&r2)[i] = scn[(size_t)col * 512 + 256 + t];
    }
    *(float4*)&bv[t * 4] = r0;
    *(float4*)&bv[(256 + t) * 4] = r1;
    *(float4*)&bv[(512 + t) * 4] = r2;
    __syncthreads();
    float a0 = 0.f, a1 = 0.f, a2 = 0.f, a3 = 0.f;
    #pragma unroll 4
    for (int k = 0; k < 768; ++k) {
      float a = At1[(size_t)k * 256 + t];
      float4 b = *(const float4*)&bv[k * 4];
      a0 += a * b.x; a1 += a * b.y; a2 += a * b.z; a3 += a * b.w;
    }
    float sv = sc1[t], bb = bi1[t];
    float4 h;
    h.x = gelu_f(a0 * sv + bb); h.y = gelu_f(a1 * sv + bb);
    h.z = gelu_f(a2 * sv + bb); h.w = gelu_f(a3 * sv + bb);
    *(float4*)&h4[t * 4] = h;
    __syncthreads();
    float c0a = 0.f, c1a = 0.f, c2a = 0.f, c3a = 0.f;
    #pragma unroll 4
    for (int k = 0; k < 256; ++k) {
      float a = At2[(size_t)k * 256 + t];
      float4 b = *(const float4*)&h4[k * 4];
      c0a += a * b.x; c1a += a * b.y; c2a += a * b.z; c3a += a * b.w;
    }
    mem_t[(size_t)(c0 + 0) * 256 + t] = c0a;
    mem_t[(size_t)(c0 + 1) * 256 + t] = c1a;
    mem_t[(size_t)(c0 + 2) * 256 + t] = c2a;
    mem_t[(size_t)(c0 + 3) * 256 + t] = c3a;
  } else if (bid < 384) {
    // ---- phase: peak + pgate MLP + pp gemm ----
    int c0 = (bid - 256) * 4; int n = c0 >> 6; int s0 = c0 & 63;
    float* hh4 = smem;          // [64][4]
    float* pin4 = smem + 256;   // [256][4]
    float conf, pnorm, dph, ang;
    compute_pk(n, fe, mfre, mfim, conf, pnorm, dph, ang);
    (void)pnorm;
    if (t < 64) {
      float w0 = pg_w1[t * 3 + 0], w1 = pg_w1[t * 3 + 1], w2 = pg_w1[t * 3 + 2];
      float sv = pg_s1[t], bb = pg_b1[t];
      float4 hv;
      #pragma unroll
      for (int i = 0; i < 4; ++i) {
        float arg = ang * (float)(s0 + i) + dph;
        float v = w0 * cosf(arg) + w1 * sinf(arg) + w2 * conf;
        ((float*)&hv)[i] = gelu_f(v * sv + bb);
      }
      *(float4*)&hh4[t * 4] = hv;
    }
    __syncthreads();
    float p0, p1, p2, p3;
    {
      float bb = pg_b2[t];
      float a0 = bb, a1 = bb, a2 = bb, a3 = bb;
      const float* wrow = pg_w2 + t * 64;
      #pragma unroll 8
      for (int j = 0; j < 64; ++j) {
        float w = wrow[j];
        float4 h = *(const float4*)&hh4[j * 4];
        a0 += w * h.x; a1 += w * h.y; a2 += w * h.z; a3 += w * h.w;
      }
      p0 = sigmoid_f(a0); p1 = sigmoid_f(a1); p2 = sigmoid_f(a2); p3 = sigmoid_f(a3);
    }
    float4 pin;
    pin.x = dn_t[(size_t)(c0 + 0) * 256 + t] * p0;
    pin.y = dn_t[(size_t)(c0 + 1) * 256 + t] * p1;
    pin.z = dn_t[(size_t)(c0 + 2) * 256 + t] * p2;
    pin.w = dn_t[(size_t)(c0 + 3) * 256 + t] * p3;
    *(float4*)&pin4[t * 4] = pin;
    __syncthreads();
    float a0 = 0.f, a1 = 0.f, a2 = 0.f, a3 = 0.f;
    #pragma unroll 4
    for (int k = 0; k < 256; ++k) {
      float a = At_pp[(size_t)k * 256 + t];
      float4 b = *(const float4*)&pin4[k * 4];
      a0 += a * b.x; a1 += a * b.y; a2 += a * b.z; a3 += a * b.w;
    }
    float sv = pp_s[t], bb = pp_b[t];
    phase_t[(size_t)(c0 + 0) * 256 + t] = gelu_f(a0 * sv + bb);
    phase_t[(size_t)(c0 + 1) * 256 + t] = gelu_f(a1 * sv + bb);
    phase_t[(size_t)(c0 + 2) * 256 + t] = gelu_f(a2 * sv + bb);
    phase_t[(size_t)(c0 + 3) * 256 + t] = gelu_f(a3 * sv + bb);
  } else {
    // ---- sgate over 2048 (n,hw) cols ----
    int c0 = (bid - 384) * 4;
    float4 r0;
    #pragma unroll
    for (int i = 0; i < 4; ++i) {
      ((float*)&r0)[i] = sp_t[(size_t)(c0 + i) * 256 + t];
    }
    *(float4*)&smem[t * 4] = r0;
    __syncthreads();
    float a0 = 0.f, a1 = 0.f, a2 = 0.f, a3 = 0.f;
    #pragma unroll 4
    for (int k = 0; k < 256; ++k) {
      float a = At_sg[(size_t)k * 256 + t];
      float4 b = *(const float4*)&smem[k * 4];
      a0 += a * b.x; a1 += a * b.y; a2 += a * b.z; a3 += a * b.w;
    }
    float sv = sg_s[t], bb = sg_b[t];
    sgate_t[(size_t)(c0 + 0) * 256 + t] = sigmoid_f(a0 * sv + bb);
    sgate_t[(size_t)(c0 + 1) * 256 + t] = sigmoid_f(a1 * sv + bb);
    sgate_t[(size_t)(c0 + 2) * 256 + t] = sigmoid_f(a2 * sv + bb);
    sgate_t[(size_t)(c0 + 3) * 256 + t] = sigmoid_f(a3 * sv + bb);
  }
}

// ---------------- router (peak recomputed inline) ----------------
__global__ __launch_bounds__(256) void router_kernel(
    const float* __restrict__ dn_t, const float* __restrict__ motion_t,
    const float* __restrict__ memory_t,
    const float* __restrict__ fe, const float* __restrict__ mfre,
    const float* __restrict__ mfim,
    const float* __restrict__ rt_w1, const float* __restrict__ rt_b1,
    const float* __restrict__ rt_w2, const float* __restrict__ rt_b2,
    float* __restrict__ bw) {
  int n = blockIdx.x; int c = threadIdx.x;
  __shared__ float ri[261];
  __shared__ float h2[64];
  __shared__ float lg[3];
  __shared__ float sc[4];
  float sum = 0.f, sq = 0.f, ad1 = 0.f, amot = 0.f, amem = 0.f, prev = 0.f;
  for (int s = 0; s < 64; ++s) {
    size_t i = ((size_t)n * 64 + s) * 256 + c;
    float d = dn_t[i];
    sum += d; sq += d * d;
    if (s > 0) ad1 += fabsf(d - prev);
    prev = d;
    amot += fabsf(motion_t[i]);
    amem += fabsf(memory_t[i] - d);
  }
  float mean = sum * (1.f / 64.f);
  float var = sq * (1.f / 64.f) - mean * mean;
  float stdc = sqrtf(fmaxf(var, 0.f));
  ri[c] = mean;
  float rstd = block_sum256(stdc, sc);
  float rad1 = block_sum256(ad1, sc);
  float rmot = block_sum256(amot, sc);
  float rmem = block_sum256(amem, sc);
  if (c == 0) {
    float conf, pnorm, dph, ang;
    compute_pk(n, fe, mfre, mfim, conf, pnorm, dph, ang);
    (void)dph; (void)ang;
    ri[256] = rstd * (1.f / 256.f);
    ri[257] = rad1 * (1.f / 16384.f);
    ri[258] = conf;
    ri[259] = pnorm;
    ri[260] = (rmem + rmot) * (1.f / 16384.f);
  }
  __syncthreads();
  if (c < 64) {
    float acc = rt_b1[c];
    const float* wrow = rt_w1 + c * 261;
    for (int i = 0; i < 261; ++i) acc += wrow[i] * ri[i];
    h2[c] = gelu_f(acc);
  }
  __syncthreads();
  if (c < 3) {
    float acc = rt_b2[c];
    const float* wrow = rt_w2 + c * 64;
    #pragma unroll 8
    for (int j = 0; j < 64; ++j) acc += wrow[j] * h2[j];
    lg[c] = acc;
  }
  __syncthreads();
  if (c == 0) {
    float m = fmaxf(lg[0], fmaxf(lg[1], lg[2]));
    float e0 = expf(lg[0] - m), e1 = expf(lg[1] - m), e2 = expf(lg[2] - m);
    float inv = 1.f / (e0 + e1 + e2);
    bw[n * 3 + 0] = e0 * inv; bw[n * 3 + 1] = e1 * inv; bw[n * 3 + 2] = e2 * inv;
  }
}

// ---------------- fused delta C4: fg-gemm + bp_prep + bp1 + bp2 + res_scale ----------------
__global__ __launch_bounds__(256) void delta_kernel(
    const float* __restrict__ dn_t, const float* __restrict__ motion_t,
    const float* __restrict__ phase_t, const float* __restrict__ mem_t,
    const float* __restrict__ bw,
    const float* __restrict__ At_fg, const float* __restrict__ fg_b,
    const float* __restrict__ At1, const float* __restrict__ sc1, const float* __restrict__ bi1,
    const float* __restrict__ At2, const float* __restrict__ rs,
    float* __restrict__ delta_t) {
  __shared__ __align__(16) float smem[5120];
  float* bv = smem;          // [1024][4]
  float* h4 = smem + 4096;   // [256][4]
  int bid = blockIdx.x;
  int c0 = bid * 4; int n = c0 >> 6; int t = threadIdx.x;
  float w0 = bw[n * 3 + 0], w1 = bw[n * 3 + 1], w2 = bw[n * 3 + 2];
  float4 fd, ffu, fmp, fmd;
  #pragma unroll
  for (int i = 0; i < 4; ++i) {
    size_t idx = (size_t)(c0 + i) * 256 + t;
    float d = dn_t[idx], m = motion_t[idx], p = phase_t[idx], me = mem_t[idx];
    ((float*)&fd)[i] = d;
    ((float*)&ffu)[i] = w0 * m + w1 * p + w2 * me;
    ((float*)&fmp)[i] = m - p;
    ((float*)&fmd)[i] = me - d;
  }
  *(float4*)&bv[t * 4] = fd;
  *(float4*)&bv[(256 + t) * 4] = ffu;
  *(float4*)&bv[(512 + t) * 4] = fmp;
  *(float4*)&bv[(768 + t) * 4] = fmd;
  __syncthreads();
  // fgate = sigmoid(fg . dn + fg_b)
  float fg0, fg1, fg2, fg3;
  {
    float a0 = 0.f, a1 = 0.f, a2 = 0.f, a3 = 0.f;
    #pragma unroll 4
    for (int k = 0; k < 256; ++k) {
      float a = At_fg[(size_t)k * 256 + t];
      float4 b = *(const float4*)&bv[k * 4];
      a0 += a * b.x; a1 += a * b.y; a2 += a * b.z; a3 += a * b.w;
    }
    float bb = fg_b[t];
    fg0 = sigmoid_f(a0 + bb); fg1 = sigmoid_f(a1 + bb);
    fg2 = sigmoid_f(a2 + bb); fg3 = sigmoid_f(a3 + bb);
  }
  // bp1
  {
    float a0 = 0.f, a1 = 0.f, a2 = 0.f, a3 = 0.f;
    #pragma unroll 4
    for (int k = 0; k < 1024; ++k) {
      float a = At1[(size_t)k * 256 + t];
      float4 b = *(const float4*)&bv[k * 4];
      a0 += a * b.x; a1 += a * b.y; a2 += a * b.z; a3 += a * b.w;
    }
    float sv = sc1[t], bb = bi1[t];
    float4 h;
    h.x = gelu_f(a0 * sv + bb); h.y = gelu_f(a1 * sv + bb);
    h.z = gelu_f(a2 * sv + bb); h.w = gelu_f(a3 * sv + bb);
    *(float4*)&h4[t * 4] = h;
  }
  __syncthreads();
  // bp2 + fgate + res_scale
  float a0 = 0.f, a1 = 0.f, a2 = 0.f, a3 = 0.f;
  #pragma unroll 4
  for (int k = 0; k < 256; ++k) {
    float a = At2[(size_t)k * 256 + t];
    float4 b = *(const float4*)&h4[k * 4];
    a0 += a * b.x; a1 += a * b.y; a2 += a * b.z; a3 += a * b.w;
  }
  float rsv = rs[t];
  delta_t[(size_t)(c0 + 0) * 256 + t] = a0 * fg0 * rsv;
  delta_t[(size_t)(c0 + 1) * 256 + t] = a1 * fg1 * rsv;
  delta_t[(size_t)(c0 + 2) * 256 + t] = a2 * fg2 * rsv;
  delta_t[(size_t)(c0 + 3) * 256 + t] = a3 * fg3 * rsv;
}

// ---------------- pass 2: out = x + delta * sgate ----------------
__global__ __launch_bounds__(256) void final_kernel(
    const float* __restrict__ x, const float* __restrict__ delta_t,
    const float* __restrict__ sgate_t, float* __restrict__ out) {
  int nc = blockIdx.x; int n = nc >> 8; int c = nc & 255;
  int t = threadIdx.x;
  __shared__ float dlt[64];
  __shared__ float4 sgs4[64];
  if (t < 64) dlt[t] = delta_t[((size_t)n * 64 + t) * 256 + c];
  ((float*)sgs4)[t] = sgate_t[((size_t)n * 256 + t) * 256 + c];
  __syncthreads();
  const float4* x4 = (const float4*)x + (size_t)nc * 4096;
  float4* o4 = (float4*)out + (size_t)nc * 4096;
  int w = t >> 6, l = t & 63;
  float4 sg = sgs4[l];
  for (int i = 0; i < 16; ++i) {
    int s = w * 16 + i;
    float d = dlt[s];
    float4 v = x4[(size_t)s * 64 + l];
    v.x += d * sg.x; v.y += d * sg.y; v.z += d * sg.z; v.w += d * sg.w;
    o4[(size_t)s * 64 + l] = v;
  }
}

} // namespace

extern "C" void kernel_launch(void* const* d_in, const int* in_sizes, int n_in,
                              void* d_out, int out_size, void* d_ws, size_t ws_size,
                              hipStream_t stream) {
  const float* x      = (const float*)d_in[0];
  const float* ln_g   = (const float*)d_in[1];
  const float* ln_b   = (const float*)d_in[2];
  const float* mb_w3  = (const float*)d_in[3];
  const float* mb_s3  = (const float*)d_in[4];
  const float* mb_b3  = (const float*)d_in[5];
  const float* mb_w5  = (const float*)d_in[6];
  const float* mb_s5  = (const float*)d_in[7];
  const float* mb_b5  = (const float*)d_in[8];
  const float* mb_w7  = (const float*)d_in[9];
  const float* mb_s7  = (const float*)d_in[10];
  const float* mb_b7  = (const float*)d_in[11];
  const float* mf_w   = (const float*)d_in[12];
  const float* mf_s   = (const float*)d_in[13];
  const float* mf_b   = (const float*)d_in[14];
  const float* pg_w1  = (const float*)d_in[15];
  const float* pg_s1  = (const float*)d_in[16];
  const float* pg_b1  = (const float*)d_in[17];
  const float* pg_w2  = (const float*)d_in[18];
  const float* pg_b2  = (const float*)d_in[19];
  const float* pp_w   = (const float*)d_in[20];
  const float* pp_s   = (const float*)d_in[21];
  const float* pp_b   = (const float*)d_in[22];
  const float* mg_w   = (const float*)d_in[23];
  const float* mg_b   = (const float*)d_in[24];
  const float* mo_w1  = (const float*)d_in[25];
  const float* mo_s1  = (const float*)d_in[26];
  const float* mo_b1  = (const float*)d_in[27];
  const float* mo_w2  = (const float*)d_in[28];
  const float* rt_w1  = (const float*)d_in[29];
  const float* rt_b1  = (const float*)d_in[30];
  const float* rt_w2  = (const float*)d_in[31];
  const float* rt_b2  = (const float*)d_in[32];
  const float* bp_w1  = (const float*)d_in[33];
  const float* bp_s1  = (const float*)d_in[34];
  const float* bp_b1  = (const float*)d_in[35];
  const float* bp_w2  = (const float*)d_in[36];
  const float* res_sc = (const float*)d_in[37];
  const float* fg_w   = (const float*)d_in[38];
  const float* fg_b   = (const float*)d_in[39];
  const float* sg_w   = (const float*)d_in[40];
  const float* sg_s   = (const float*)d_in[41];
  const float* sg_b   = (const float*)d_in[42];
  float* ws = (float*)d_ws;
  float* out = (float*)d_out;
  unsigned short* wfrag = (unsigned short*)(ws + O_WFRAG);
  unsigned short* im2   = (unsigned short*)(ws + O_IM2);

  weights_kernel<<<2976, 256, 0, stream>>>(mf_w, mg_w, mo_w1, mo_w2, pp_w, bp_w1,
      bp_w2, fg_w, sg_w, ws, mb_w3, mb_w5, mb_w7, wfrag);
  reduce_x_kernel<<<2048, 256, 0, stream>>>(x, ws + O_DESC, ws + O_SPT);
  ln_kernel<<<512, 256, 0, stream>>>(ws + O_DESC, ln_g, ln_b, ws + O_DN);
  post_ln_kernel<<<1736, 256, 0, stream>>>(ws + O_DN, ws + O_ATMG, mg_b, ws + O_GATE,
      im2, ws + O_FE, ws + O_MFRE, ws + O_MFIM);
  conv_scan_kernel<<<400, 256, 0, stream>>>(wfrag, im2, ws + O_CONVC,
      ws + O_DN, ws + O_GATE, ws + O_SCN);
  mid_kernel<<<896, 256, 0, stream>>>(ws + O_CONVC, mb_s3, mb_b3, mb_s5, mb_b5,
      mb_s7, mb_b7, ws + O_ATMF, mf_s, mf_b, ws + O_MOT,
      ws + O_DN, ws + O_SCN, ws + O_ATMO1, mo_s1, mo_b1, ws + O_ATMO2, ws + O_MEM,
      ws + O_FE, ws + O_MFRE, ws + O_MFIM,
      pg_w1, pg_s1, pg_b1, pg_w2, pg_b2, ws + O_ATPP, pp_s, pp_b, ws + O_PHASE,
      ws + O_ATSG, ws + O_SPT, sg_s, sg_b, ws + O_SGATE);
  router_kernel<<<8, 256, 0, stream>>>(ws + O_DN, ws + O_MOT, ws + O_MEM,
      ws + O_FE, ws + O_MFRE, ws + O_MFIM, rt_w1, rt_b1, rt_w2, rt_b2, ws + O_BW);
  delta_kernel<<<128, 256, 0, stream>>>(ws + O_DN, ws + O_MOT, ws + O_PHASE, ws + O_MEM,
      ws + O_BW, ws + O_ATFG, fg_b, ws + O_ATBP1, bp_s1, bp_b1, ws + O_ATBP2, res_sc,
      ws + O_DELTA);
  final_kernel<<<2048, 256, 0, stream>>>(x, ws + O_DELTA, ws + O_SGATE, out);
}

// Round 3
// 564.389 us; speedup vs baseline: 1.1308x; 1.1308x over previous
//
#include <hip/hip_runtime.h>
#include <math.h>

namespace {

constexpr int N_ = 8, C_ = 256, S_ = 64, HW_ = 256;
constexpr int NS = N_ * S_;      // 512 columns (n,s)
constexpr int NHW = N_ * HW_;    // 2048 columns (n,hw)

// ---- workspace layout (float offsets) ----
constexpr size_t O_DESC  = 0;            // [512][256]
constexpr size_t O_DN    = 131072;
constexpr size_t O_MOT   = 393216;
constexpr size_t O_GATE  = 524288;
constexpr size_t O_MEM   = 786432;
constexpr size_t O_PHASE = 1048576;
constexpr size_t O_DELTA = 1441792;
constexpr size_t O_SCN   = 1572864;      // [512][512] scan out: fwd c<256, bwd c>=256
constexpr size_t O_SPT   = 2752512;      // [2048][256]
constexpr size_t O_SGATE = 3276800;      // [2048][256]
constexpr size_t O_FE    = 3801088;      // 264 used
constexpr size_t O_MFRE  = 3801600;
constexpr size_t O_MFIM  = 3802112;
constexpr size_t O_BW    = 3802656;      // [n][3]
constexpr size_t O_ATMF  = 3802688;
constexpr size_t O_ATMG  = 3868224;
constexpr size_t O_ATMO1 = 3999296;
constexpr size_t O_ATMO2 = 4195904;
constexpr size_t O_ATPP  = 4261440;
constexpr size_t O_ATBP1 = 4326976;
constexpr size_t O_ATBP2 = 4589120;
constexpr size_t O_ATFG  = 4654656;
constexpr size_t O_ATSG  = 4720192;
constexpr size_t O_WFRAG = 4785728;      // bf16 [168 kchunk][48 m16][64 lane][8]
constexpr size_t O_IM2   = 6850112;      // bf16 [168 kchunk][32 c16][64 lane][8]
constexpr size_t O_CONVC = 8226368;      // fp32 [4 kp][768][512]

typedef __attribute__((ext_vector_type(4))) float f32x4;
typedef __attribute__((ext_vector_type(8))) short s16x8;
typedef __attribute__((ext_vector_type(8))) unsigned short u16x8;

__device__ __forceinline__ float gelu_f(float v) {
  return 0.5f * v * (1.0f + erff(v * 0.70710678118654752f));
}
__device__ __forceinline__ float sigmoid_f(float v) {
  return 1.0f / (1.0f + expf(-v));
}
__device__ __forceinline__ unsigned short f2bf(float f) {
  unsigned int u = __float_as_uint(f);
  u += 0x7fffu + ((u >> 16) & 1u);
  return (unsigned short)(u >> 16);
}

// block (256 threads) sum with broadcast; scratch = 4 floats in LDS
__device__ __forceinline__ float block_sum256(float v, float* scratch) {
  #pragma unroll
  for (int off = 32; off; off >>= 1) v += __shfl_down(v, off, 64);
  int w = threadIdx.x >> 6;
  __syncthreads();
  if ((threadIdx.x & 63) == 0) scratch[w] = v;
  __syncthreads();
  return scratch[0] + scratch[1] + scratch[2] + scratch[3];
}

// peak params per n (26-element serial scan, uniform loads — bit-identical in all callers)
__device__ __forceinline__ void compute_pk(
    int n, const float* __restrict__ fe, const float* __restrict__ mfre,
    const float* __restrict__ mfim,
    float& conf, float& pnorm, float& dph, float& ang) {
  const float* f = fe + n * 33;
  float best = f[7]; int bidx = 0; float hs = 0.f;
  #pragma unroll
  for (int i = 0; i < 26; ++i) {
    float v = f[7 + i];
    hs += v;
    if (v > best) { best = v; bidx = i; }
  }
  int pi = bidx + 7;
  conf = best / fmaxf(hs, 1e-6f);
  pnorm = (float)pi * (1.f / 32.f);
  dph = atan2f(mfim[n * 33 + pi], mfre[n * 33 + pi]);
  ang = (6.283185307179586f / 64.f) * (float)pi;
}

// ---------------- weight prep: 1x1 transpose + conv A-fragment pack, one launch ----------------
__global__ __launch_bounds__(256) void weights_kernel(
    const float* __restrict__ wmf, const float* __restrict__ wmg,
    const float* __restrict__ wmo1, const float* __restrict__ wmo2,
    const float* __restrict__ wpp, const float* __restrict__ wbp1,
    const float* __restrict__ wbp2, const float* __restrict__ wfg,
    const float* __restrict__ wsg, float* __restrict__ ws,
    const float* __restrict__ w3, const float* __restrict__ w5,
    const float* __restrict__ w7, unsigned short* __restrict__ wf) {
  int bid = blockIdx.x;
  if (bid < 960) {
    __shared__ float tile[32][33];
    int xt = bid % 120, yt = bid / 120;
    const float* src; float* dst; int K;
    if      (xt < 8)   { src = wmf;  dst = ws + O_ATMF;  K = 256;  }
    else if (xt < 24)  { src = wmg;  dst = ws + O_ATMG;  K = 512;  xt -= 8;  }
    else if (xt < 48)  { src = wmo1; dst = ws + O_ATMO1; K = 768;  xt -= 24; }
    else if (xt < 56)  { src = wmo2; dst = ws + O_ATMO2; K = 256;  xt -= 48; }
    else if (xt < 64)  { src = wpp;  dst = ws + O_ATPP;  K = 256;  xt -= 56; }
    else if (xt < 96)  { src = wbp1; dst = ws + O_ATBP1; K = 1024; xt -= 64; }
    else if (xt < 104) { src = wbp2; dst = ws + O_ATBP2; K = 256;  xt -= 96; }
    else if (xt < 112) { src = wfg;  dst = ws + O_ATFG;  K = 256;  xt -= 104;}
    else               { src = wsg;  dst = ws + O_ATSG;  K = 256;  xt -= 112;}
    int tx = threadIdx.x & 31, ty = threadIdx.x >> 5;
    int c = xt * 32 + tx;
    #pragma unroll
    for (int i = 0; i < 4; ++i) {
      int r = yt * 32 + ty + i * 8;
      tile[ty + i * 8][tx] = src[(size_t)r * K + c];
    }
    __syncthreads();
    #pragma unroll
    for (int i = 0; i < 4; ++i) {
      int cc = xt * 32 + ty + i * 8;
      dst[(size_t)cc * 256 + yt * 32 + tx] = tile[tx][ty + i * 8];
    }
  } else {
    int g = (bid - 960) * 256 + threadIdx.x;       // one lane-slot
    int lane = g & 63;
    int m16 = (g >> 6) % 48;
    int kchunk = (g >> 6) / 48;
    int o = m16 * 16 + (lane & 15);
    int conv = o >> 8, oc = o & 255;
    int q = lane >> 4;
    u16x8 outv;
    #pragma unroll
    for (int j = 0; j < 8; ++j) {
      int k = kchunk * 32 + q * 8 + j;
      int ic = k / 7;
      int tau = k - ic * 7 - 3;
      float v = 0.f;
      if (conv == 0) {
        if (tau >= -1 && tau <= 1) v = w3[((size_t)oc * 768 + ic) * 3 + (tau + 1)];
      } else if (conv == 1) {
        if (tau >= -2 && tau <= 2) v = w5[((size_t)oc * 768 + ic) * 5 + (tau + 2)];
      } else {
        v = w7[((size_t)oc * 768 + ic) * 7 + (tau + 3)];
      }
      outv[j] = f2bf(v);
    }
    *((u16x8*)wf + g) = outv;
  }
}

// ---------------- pass 1: x reductions ----------------
__global__ __launch_bounds__(256) void reduce_x_kernel(
    const float* __restrict__ x, float* __restrict__ desc_t, float* __restrict__ sp_t) {
  int nc = blockIdx.x; int n = nc >> 8; int c = nc & 255;
  int t = threadIdx.x; int w = t >> 6; int l = t & 63;
  const float4* x4 = (const float4*)x + (size_t)nc * 4096;
  float4 sa = {0.f, 0.f, 0.f, 0.f};
  for (int i = 0; i < 16; ++i) {
    int s = w * 16 + i;
    float4 v = x4[(size_t)s * 64 + l];
    sa.x += v.x; sa.y += v.y; sa.z += v.z; sa.w += v.w;
    float ds = v.x + v.y + v.z + v.w;
    #pragma unroll
    for (int off = 32; off; off >>= 1) ds += __shfl_down(ds, off, 64);
    if (l == 0) desc_t[((size_t)n * 64 + s) * 256 + c] = ds * (1.f / 256.f);
  }
  __shared__ float4 lsp[4][64];
  lsp[w][l] = sa;
  __syncthreads();
  if (t < 64) {
    float4 a = lsp[0][t], b = lsp[1][t], c2 = lsp[2][t], d = lsp[3][t];
    float4 tot;
    tot.x = a.x + b.x + c2.x + d.x; tot.y = a.y + b.y + c2.y + d.y;
    tot.z = a.z + b.z + c2.z + d.z; tot.w = a.w + b.w + c2.w + d.w;
    size_t base = ((size_t)n * 256 + t * 4) * 256 + c;
    sp_t[base]       = tot.x * (1.f / 64.f);
    sp_t[base + 256] = tot.y * (1.f / 64.f);
    sp_t[base + 512] = tot.z * (1.f / 64.f);
    sp_t[base + 768] = tot.w * (1.f / 64.f);
  }
}

// ---------------- LayerNorm over C per (n,s) ----------------
__global__ __launch_bounds__(256) void ln_kernel(
    const float* __restrict__ desc_t, const float* __restrict__ g,
    const float* __restrict__ b, float* __restrict__ dn_t) {
  __shared__ float sc[4];
  int col = blockIdx.x; int t = threadIdx.x;
  float v = desc_t[(size_t)col * 256 + t];
  float s1 = block_sum256(v, sc);
  float s2 = block_sum256(v * v, sc);
  float mu = s1 * (1.f / 256.f);
  float var = s2 * (1.f / 256.f) - mu * mu;
  float r = rsqrtf(var + 1e-5f);
  dn_t[(size_t)col * 256 + t] = (v - mu) * r * g[t] + b[t];
}

// ---------------- mega: gate C4 (128) + im2col (1344) + fft (264) ----------------
__global__ __launch_bounds__(256) void post_ln_kernel(
    const float* __restrict__ dn_t, const float* __restrict__ At_mg,
    const float* __restrict__ mg_b, float* __restrict__ gate_t,
    unsigned short* __restrict__ imf,
    float* __restrict__ fe, float* __restrict__ mfre, float* __restrict__ mfim) {
  __shared__ __align__(16) float smem[2048];
  int bid = blockIdx.x;
  int t = threadIdx.x;
  if (bid < 128) {
    // ---- gate, 4 cols/block ----
    int c0 = bid * 4;
    float4 f0, f1;
    {
      float d[4], a[4];
      #pragma unroll
      for (int i = 0; i < 4; ++i) {
        int col = c0 + i; int s = col & 63;
        float dd = dn_t[(size_t)col * 256 + t];
        float d1 = (s >= 1) ? dd - dn_t[(size_t)(col - 1) * 256 + t] : 0.f;
        d[i] = dd; a[i] = fabsf(d1);
      }
      f0.x = d[0]; f0.y = d[1]; f0.z = d[2]; f0.w = d[3];
      f1.x = a[0]; f1.y = a[1]; f1.z = a[2]; f1.w = a[3];
    }
    *(float4*)&smem[t * 4] = f0;
    *(float4*)&smem[(256 + t) * 4] = f1;
    __syncthreads();
    float a0 = 0.f, a1 = 0.f, a2 = 0.f, a3 = 0.f;
    #pragma unroll 4
    for (int k = 0; k < 512; ++k) {
      float a = At_mg[(size_t)k * 256 + t];
      float4 b = *(const float4*)&smem[k * 4];
      a0 += a * b.x; a1 += a * b.y; a2 += a * b.z; a3 += a * b.w;
    }
    float bb = mg_b[t];
    gate_t[(size_t)(c0 + 0) * 256 + t] = sigmoid_f(a0 + bb);
    gate_t[(size_t)(c0 + 1) * 256 + t] = sigmoid_f(a1 + bb);
    gate_t[(size_t)(c0 + 2) * 256 + t] = sigmoid_f(a2 + bb);
    gate_t[(size_t)(c0 + 3) * 256 + t] = sigmoid_f(a3 + bb);
  } else if (bid < 1472) {
    // ---- im2col B-fragments ----
    int g = (bid - 128) * 256 + t;
    int lane = g & 63;
    int c16 = (g >> 6) % 32;
    int kchunk = (g >> 6) / 32;
    int col = c16 * 16 + (lane & 15);
    int n = col >> 6, s = col & 63;
    int q = lane >> 4;
    const float* base = dn_t + (size_t)n * 16384;
    u16x8 outv;
    #pragma unroll
    for (int j = 0; j < 8; ++j) {
      int k = kchunk * 32 + q * 8 + j;
      int ic = k / 7;
      int tau = k - ic * 7 - 3;
      int stream = ic >> 8, c = ic & 255;
      int sp = s + tau;
      float v = 0.f;
      if (sp >= 0 && sp < 64) {
        float d = base[(size_t)sp * 256 + c];
        if (stream == 0) v = d;
        else if (stream == 1) v = (sp >= 1) ? d - base[(size_t)(sp - 1) * 256 + c] : 0.f;
        else v = (sp >= 2) ? d - base[(size_t)(sp - 2) * 256 + c] : 0.f;
      }
      outv[j] = f2bf(v);
    }
    *((u16x8*)imf + g) = outv;
  } else {
    // ---- rFFT (direct DFT) ----
    int b = bid - 1472; int n = b / 33; int f = b % 33;
    float* cs = smem; float* sn = smem + 64; float* scr = smem + 128;
    if (t < 64) {
      int ft = (f * t) & 63;
      float ang = -6.283185307179586f * (float)ft * (1.f / 64.f);
      cs[t] = cosf(ang); sn[t] = sinf(ang);
    }
    __syncthreads();
    float re = 0.f, im = 0.f;
    const float* base = dn_t + (size_t)n * 16384 + t;
    for (int s = 0; s < 64; ++s) {
      float v = base[(size_t)s * 256];
      re += v * cs[s]; im += v * sn[s];
    }
    re *= 0.125f; im *= 0.125f;   // ortho 1/sqrt(64)
    float mag = sqrtf(re * re + im * im);
    float sm = block_sum256(mag, scr);
    float sr = block_sum256(re, scr);
    float si = block_sum256(im, scr);
    if (t == 0) {
      fe[b]   = sm * (1.f / 256.f);
      mfre[b] = sr * (1.f / 256.f);
      mfim[b] = si * (1.f / 256.f);
    }
  }
}

// ---------------- mega: conv MFMA (384) + gated scan (16) ----------------
__global__ __launch_bounds__(256) void conv_scan_kernel(
    const unsigned short* __restrict__ wf, const unsigned short* __restrict__ imf,
    float* __restrict__ partial,
    const float* __restrict__ dn_t, const float* __restrict__ gate_t,
    float* __restrict__ scn) {
  __shared__ float smem[16384];   // 64 KB, used by scan blocks only
  int bid = blockIdx.x;
  int t = threadIdx.x;
  if (bid < 384) {
    int mt = bid % 12; int rem = bid / 12;
    int nt = rem % 8; int kp = rem / 8;
    int lane = t & 63;
    int w = t >> 6;
    int m16 = mt * 4 + w;
    const s16x8* wfp = (const s16x8*)wf;
    const s16x8* imp = (const s16x8*)imf;
    f32x4 acc0 = {0.f,0.f,0.f,0.f}, acc1 = {0.f,0.f,0.f,0.f};
    f32x4 acc2 = {0.f,0.f,0.f,0.f}, acc3 = {0.f,0.f,0.f,0.f};
    #pragma unroll 2
    for (int cc = 0; cc < 42; ++cc) {
      int kc = kp * 42 + cc;
      s16x8 a = wfp[(size_t)(kc * 48 + m16) * 64 + lane];
      s16x8 b0 = imp[(size_t)(kc * 32 + nt * 4 + 0) * 64 + lane];
      s16x8 b1 = imp[(size_t)(kc * 32 + nt * 4 + 1) * 64 + lane];
      s16x8 b2 = imp[(size_t)(kc * 32 + nt * 4 + 2) * 64 + lane];
      s16x8 b3 = imp[(size_t)(kc * 32 + nt * 4 + 3) * 64 + lane];
      acc0 = __builtin_amdgcn_mfma_f32_16x16x32_bf16(a, b0, acc0, 0, 0, 0);
      acc1 = __builtin_amdgcn_mfma_f32_16x16x32_bf16(a, b1, acc1, 0, 0, 0);
      acc2 = __builtin_amdgcn_mfma_f32_16x16x32_bf16(a, b2, acc2, 0, 0, 0);
      acc3 = __builtin_amdgcn_mfma_f32_16x16x32_bf16(a, b3, acc3, 0, 0, 0);
    }
    int q = lane >> 4, ln = lane & 15;
    int o0 = m16 * 16 + q * 4;
    float* pb = partial + (size_t)kp * 393216;
    #pragma unroll
    for (int r = 0; r < 4; ++r) {
      size_t row = (size_t)(o0 + r) * 512;
      pb[row + (nt * 4 + 0) * 16 + ln] = acc0[r];
      pb[row + (nt * 4 + 1) * 16 + ln] = acc1[r];
      pb[row + (nt * 4 + 2) * 16 + ln] = acc2[r];
      pb[row + (nt * 4 + 3) * 16 + ln] = acc3[r];
    }
  } else {
    int idx = bid - 384;
    int n = idx >> 1, half = idx & 1;
    float* ld = smem;
    float* lg = smem + 8192;
    const float* dsrc = dn_t + (size_t)n * 16384 + half * 128;
    const float* gsrc = gate_t + (size_t)n * 16384 + half * 128;
    for (int i = t; i < 8192; i += 256) {
      int s = i >> 7, j = i & 127;
      ld[i] = dsrc[(size_t)s * 256 + j];
      lg[i] = gsrc[(size_t)s * 256 + j];
    }
    __syncthreads();
    int cl = t & 127;
    int c = half * 128 + cl;
    size_t ob = (size_t)n * 64 * 512 + c;
    if (t < 128) {
      float st = ld[cl];
      scn[ob] = st;
      for (int s = 1; s < 64; ++s) {
        float g = lg[s * 128 + cl], d = ld[s * 128 + cl];
        st = g * st + (1.f - g) * d;
        scn[ob + (size_t)s * 512] = st;
      }
    } else {
      float st = ld[63 * 128 + cl];
      scn[ob + (size_t)63 * 512 + 256] = st;
      for (int s = 62; s >= 0; --s) {
        float g = lg[s * 128 + cl], d = ld[s * 128 + cl];
        st = g * st + (1.f - g) * d;
        scn[ob + (size_t)s * 512 + 256] = st;
      }
    }
  }
}

// ---------------- mega: motion C4 (128) + memory C4 (128) + phase C4 (128) + sgate C4 (512) ----------------
__global__ __launch_bounds__(256) void mid_kernel(
    const float* __restrict__ P,
    const float* __restrict__ s3, const float* __restrict__ b3,
    const float* __restrict__ s5, const float* __restrict__ b5,
    const float* __restrict__ s7, const float* __restrict__ b7,
    const float* __restrict__ At_mf, const float* __restrict__ mf_s,
    const float* __restrict__ mf_b, float* __restrict__ motion_t,
    const float* __restrict__ dn_t, const float* __restrict__ scn,
    const float* __restrict__ At1, const float* __restrict__ sc1, const float* __restrict__ bi1,
    const float* __restrict__ At2, float* __restrict__ mem_t,
    const float* __restrict__ fe, const float* __restrict__ mfre, const float* __restrict__ mfim,
    const float* __restrict__ pg_w1, const float* __restrict__ pg_s1, const float* __restrict__ pg_b1,
    const float* __restrict__ pg_w2, const float* __restrict__ pg_b2,
    const float* __restrict__ At_pp, const float* __restrict__ pp_s, const float* __restrict__ pp_b,
    float* __restrict__ phase_t,
    const float* __restrict__ At_sg, const float* __restrict__ sp_t,
    const float* __restrict__ sg_s, const float* __restrict__ sg_b,
    float* __restrict__ sgate_t) {
  __shared__ __align__(16) float smem[4096];
  int bid = blockIdx.x;
  int t = threadIdx.x;
  if (bid < 128) {
    // ---- motion: combine conv partials + bn/gelu/avg + mf gemm ----
    int c0 = bid * 4;
    float4 v3 = {0,0,0,0}, v5 = {0,0,0,0}, v7 = {0,0,0,0};
    #pragma unroll
    for (int kp = 0; kp < 4; ++kp) {
      const float* base = P + (size_t)kp * 393216 + c0;
      float4 x3 = *(const float4*)(base + (size_t)t * 512);
      float4 x5 = *(const float4*)(base + (size_t)(t + 256) * 512);
      float4 x7 = *(const float4*)(base + (size_t)(t + 512) * 512);
      v3.x += x3.x; v3.y += x3.y; v3.z += x3.z; v3.w += x3.w;
      v5.x += x5.x; v5.y += x5.y; v5.z += x5.z; v5.w += x5.w;
      v7.x += x7.x; v7.y += x7.y; v7.z += x7.z; v7.w += x7.w;
    }
    float s3v = s3[t], b3v = b3[t], s5v = s5[t], b5v = b5[t], s7v = s7[t], b7v = b7[t];
    float4 ms;
    ms.x = (gelu_f(v3.x*s3v+b3v) + gelu_f(v5.x*s5v+b5v) + gelu_f(v7.x*s7v+b7v)) * (1.f/3.f);
    ms.y = (gelu_f(v3.y*s3v+b3v) + gelu_f(v5.y*s5v+b5v) + gelu_f(v7.y*s7v+b7v)) * (1.f/3.f);
    ms.z = (gelu_f(v3.z*s3v+b3v) + gelu_f(v5.z*s5v+b5v) + gelu_f(v7.z*s7v+b7v)) * (1.f/3.f);
    ms.w = (gelu_f(v3.w*s3v+b3v) + gelu_f(v5.w*s5v+b5v) + gelu_f(v7.w*s7v+b7v)) * (1.f/3.f);
    *(float4*)&smem[t * 4] = ms;
    __syncthreads();
    float a0 = 0.f, a1 = 0.f, a2 = 0.f, a3 = 0.f;
    #pragma unroll 4
    for (int k = 0; k < 256; ++k) {
      float a = At_mf[(size_t)k * 256 + t];
      float4 b = *(const float4*)&smem[k * 4];
      a0 += a * b.x; a1 += a * b.y; a2 += a * b.z; a3 += a * b.w;
    }
    float sv = mf_s[t], bv2 = mf_b[t];
    motion_t[(size_t)(c0 + 0) * 256 + t] = gelu_f(a0 * sv + bv2);
    motion_t[(size_t)(c0 + 1) * 256 + t] = gelu_f(a1 * sv + bv2);
    motion_t[(size_t)(c0 + 2) * 256 + t] = gelu_f(a2 * sv + bv2);
    motion_t[(size_t)(c0 + 3) * 256 + t] = gelu_f(a3 * sv + bv2);
  } else if (bid < 256) {
    // ---- memory: mo1 + mo2 ----
    int c0 = (bid - 128) * 4;
    float* bv = smem;          // [768][4]
    float* h4 = smem + 3072;   // [256][4]
    float4 r0, r1, r2;
    #pragma unroll
    for (int i = 0; i < 4; ++i) {
      int col = c0 + i;
      ((float*)&r0)[i] = dn_t[(size_t)col * 256 + t];
      ((float*)&r1)[i] = scn[(size_t)col * 512 + t];
      ((float*)&r2)[i] = scn[(size_t)col * 512 + 256 + t];
    }
    *(float4*)&bv[t * 4] = r0;
    *(float4*)&bv[(256 + t) * 4] = r1;
    *(float4*)&bv[(512 + t) * 4] = r2;
    __syncthreads();
    float a0 = 0.f, a1 = 0.f, a2 = 0.f, a3 = 0.f;
    #pragma unroll 4
    for (int k = 0; k < 768; ++k) {
      float a = At1[(size_t)k * 256 + t];
      float4 b = *(const float4*)&bv[k * 4];
      a0 += a * b.x; a1 += a * b.y; a2 += a * b.z; a3 += a * b.w;
    }
    float sv = sc1[t], bb = bi1[t];
    float4 h;
    h.x = gelu_f(a0 * sv + bb); h.y = gelu_f(a1 * sv + bb);
    h.z = gelu_f(a2 * sv + bb); h.w = gelu_f(a3 * sv + bb);
    *(float4*)&h4[t * 4] = h;
    __syncthreads();
    float c0a = 0.f, c1a = 0.f, c2a = 0.f, c3a = 0.f;
    #pragma unroll 4
    for (int k = 0; k < 256; ++k) {
      float a = At2[(size_t)k * 256 + t];
      float4 b = *(const float4*)&h4[k * 4];
      c0a += a * b.x; c1a += a * b.y; c2a += a * b.z; c3a += a * b.w;
    }
    mem_t[(size_t)(c0 + 0) * 256 + t] = c0a;
    mem_t[(size_t)(c0 + 1) * 256 + t] = c1a;
    mem_t[(size_t)(c0 + 2) * 256 + t] = c2a;
    mem_t[(size_t)(c0 + 3) * 256 + t] = c3a;
  } else if (bid < 384) {
    // ---- phase: peak + pgate MLP + pp gemm ----
    int c0 = (bid - 256) * 4; int n = c0 >> 6; int s0 = c0 & 63;
    float* hh4 = smem;          // [64][4]
    float* pin4 = smem + 256;   // [256][4]
    float conf, pnorm, dph, ang;
    compute_pk(n, fe, mfre, mfim, conf, pnorm, dph, ang);
    (void)pnorm;
    if (t < 64) {
      float w0 = pg_w1[t * 3 + 0], w1 = pg_w1[t * 3 + 1], w2 = pg_w1[t * 3 + 2];
      float sv = pg_s1[t], bb = pg_b1[t];
      float4 hv;
      #pragma unroll
      for (int i = 0; i < 4; ++i) {
        float arg = ang * (float)(s0 + i) + dph;
        float v = w0 * cosf(arg) + w1 * sinf(arg) + w2 * conf;
        ((float*)&hv)[i] = gelu_f(v * sv + bb);
      }
      *(float4*)&hh4[t * 4] = hv;
    }
    __syncthreads();
    float p0, p1, p2, p3;
    {
      float bb = pg_b2[t];
      float a0 = bb, a1 = bb, a2 = bb, a3 = bb;
      const float* wrow = pg_w2 + t * 64;
      #pragma unroll 8
      for (int j = 0; j < 64; ++j) {
        float w = wrow[j];
        float4 h = *(const float4*)&hh4[j * 4];
        a0 += w * h.x; a1 += w * h.y; a2 += w * h.z; a3 += w * h.w;
      }
      p0 = sigmoid_f(a0); p1 = sigmoid_f(a1); p2 = sigmoid_f(a2); p3 = sigmoid_f(a3);
    }
    float4 pin;
    pin.x = dn_t[(size_t)(c0 + 0) * 256 + t] * p0;
    pin.y = dn_t[(size_t)(c0 + 1) * 256 + t] * p1;
    pin.z = dn_t[(size_t)(c0 + 2) * 256 + t] * p2;
    pin.w = dn_t[(size_t)(c0 + 3) * 256 + t] * p3;
    *(float4*)&pin4[t * 4] = pin;
    __syncthreads();
    float a0 = 0.f, a1 = 0.f, a2 = 0.f, a3 = 0.f;
    #pragma unroll 4
    for (int k = 0; k < 256; ++k) {
      float a = At_pp[(size_t)k * 256 + t];
      float4 b = *(const float4*)&pin4[k * 4];
      a0 += a * b.x; a1 += a * b.y; a2 += a * b.z; a3 += a * b.w;
    }
    float sv = pp_s[t], bb = pp_b[t];
    phase_t[(size_t)(c0 + 0) * 256 + t] = gelu_f(a0 * sv + bb);
    phase_t[(size_t)(c0 + 1) * 256 + t] = gelu_f(a1 * sv + bb);
    phase_t[(size_t)(c0 + 2) * 256 + t] = gelu_f(a2 * sv + bb);
    phase_t[(size_t)(c0 + 3) * 256 + t] = gelu_f(a3 * sv + bb);
  } else {
    // ---- sgate over 2048 (n,hw) cols ----
    int c0 = (bid - 384) * 4;
    float4 r0;
    #pragma unroll
    for (int i = 0; i < 4; ++i) {
      ((float*)&r0)[i] = sp_t[(size_t)(c0 + i) * 256 + t];
    }
    *(float4*)&smem[t * 4] = r0;
    __syncthreads();
    float a0 = 0.f, a1 = 0.f, a2 = 0.f, a3 = 0.f;
    #pragma unroll 4
    for (int k = 0; k < 256; ++k) {
      float a = At_sg[(size_t)k * 256 + t];
      float4 b = *(const float4*)&smem[k * 4];
      a0 += a * b.x; a1 += a * b.y; a2 += a * b.z; a3 += a * b.w;
    }
    float sv = sg_s[t], bb = sg_b[t];
    sgate_t[(size_t)(c0 + 0) * 256 + t] = sigmoid_f(a0 * sv + bb);
    sgate_t[(size_t)(c0 + 1) * 256 + t] = sigmoid_f(a1 * sv + bb);
    sgate_t[(size_t)(c0 + 2) * 256 + t] = sigmoid_f(a2 * sv + bb);
    sgate_t[(size_t)(c0 + 3) * 256 + t] = sigmoid_f(a3 * sv + bb);
  }
}

// ---------------- router (peak recomputed inline) ----------------
__global__ __launch_bounds__(256) void router_kernel(
    const float* __restrict__ dn_t, const float* __restrict__ motion_t,
    const float* __restrict__ memory_t,
    const float* __restrict__ fe, const float* __restrict__ mfre,
    const float* __restrict__ mfim,
    const float* __restrict__ rt_w1, const float* __restrict__ rt_b1,
    const float* __restrict__ rt_w2, const float* __restrict__ rt_b2,
    float* __restrict__ bw) {
  int n = blockIdx.x; int c = threadIdx.x;
  __shared__ float ri[261];
  __shared__ float h2[64];
  __shared__ float lg[3];
  __shared__ float sc[4];
  float sum = 0.f, sq = 0.f, ad1 = 0.f, amot = 0.f, amem = 0.f, prev = 0.f;
  for (int s = 0; s < 64; ++s) {
    size_t i = ((size_t)n * 64 + s) * 256 + c;
    float d = dn_t[i];
    sum += d; sq += d * d;
    if (s > 0) ad1 += fabsf(d - prev);
    prev = d;
    amot += fabsf(motion_t[i]);
    amem += fabsf(memory_t[i] - d);
  }
  float mean = sum * (1.f / 64.f);
  float var = sq * (1.f / 64.f) - mean * mean;
  float stdc = sqrtf(fmaxf(var, 0.f));
  ri[c] = mean;
  float rstd = block_sum256(stdc, sc);
  float rad1 = block_sum256(ad1, sc);
  float rmot = block_sum256(amot, sc);
  float rmem = block_sum256(amem, sc);
  if (c == 0) {
    float conf, pnorm, dph, ang;
    compute_pk(n, fe, mfre, mfim, conf, pnorm, dph, ang);
    (void)dph; (void)ang;
    ri[256] = rstd * (1.f / 256.f);
    ri[257] = rad1 * (1.f / 16384.f);
    ri[258] = conf;
    ri[259] = pnorm;
    ri[260] = (rmem + rmot) * (1.f / 16384.f);
  }
  __syncthreads();
  if (c < 64) {
    float acc = rt_b1[c];
    const float* wrow = rt_w1 + c * 261;
    for (int i = 0; i < 261; ++i) acc += wrow[i] * ri[i];
    h2[c] = gelu_f(acc);
  }
  __syncthreads();
  if (c < 3) {
    float acc = rt_b2[c];
    const float* wrow = rt_w2 + c * 64;
    #pragma unroll 8
    for (int j = 0; j < 64; ++j) acc += wrow[j] * h2[j];
    lg[c] = acc;
  }
  __syncthreads();
  if (c == 0) {
    float m = fmaxf(lg[0], fmaxf(lg[1], lg[2]));
    float e0 = expf(lg[0] - m), e1 = expf(lg[1] - m), e2 = expf(lg[2] - m);
    float inv = 1.f / (e0 + e1 + e2);
    bw[n * 3 + 0] = e0 * inv; bw[n * 3 + 1] = e1 * inv; bw[n * 3 + 2] = e2 * inv;
  }
}

// ---------------- delta: block-per-col, wave K-split, float4 At loads ----------------
// each wave handles K/4 of the k-range; lane ln computes outputs ln*4..ln*4+3;
// partials reduced via LDS [4 waves][64 lanes] float4.
__global__ __launch_bounds__(256) void delta_kernel(
    const float* __restrict__ dn_t, const float* __restrict__ motion_t,
    const float* __restrict__ phase_t, const float* __restrict__ mem_t,
    const float* __restrict__ bw,
    const float* __restrict__ At_fg, const float* __restrict__ fg_b,
    const float* __restrict__ At1, const float* __restrict__ sc1, const float* __restrict__ bi1,
    const float* __restrict__ At2, const float* __restrict__ rs,
    float* __restrict__ delta_t) {
  __shared__ __align__(16) float bv[1024];
  __shared__ __align__(16) float4 part[4][64];
  __shared__ float hs[256];
  __shared__ float fgs[256];
  int col = blockIdx.x; int n = col >> 6; int t = threadIdx.x;
  int w = t >> 6, ln = t & 63;
  int oq = t >> 2, oc = t & 3;
  float w0 = bw[n * 3 + 0], w1 = bw[n * 3 + 1], w2 = bw[n * 3 + 2];
  size_t idx = (size_t)col * 256 + t;
  float d = dn_t[idx], m = motion_t[idx], p = phase_t[idx], me = mem_t[idx];
  bv[t]       = d;
  bv[256 + t] = w0 * m + w1 * p + w2 * me;
  bv[512 + t] = m - p;
  bv[768 + t] = me - d;
  __syncthreads();
  // fgate = sigmoid(fg . dn + fg_b); K=256, wave range 64
  {
    float a0 = 0.f, a1 = 0.f, a2 = 0.f, a3 = 0.f;
    int k0 = w * 64;
    #pragma unroll 4
    for (int k = k0; k < k0 + 64; ++k) {
      float b = bv[k];
      float4 a = *(const float4*)(At_fg + (size_t)k * 256 + ln * 4);
      a0 += a.x * b; a1 += a.y * b; a2 += a.z * b; a3 += a.w * b;
    }
    float4 pr; pr.x = a0; pr.y = a1; pr.z = a2; pr.w = a3;
    part[w][ln] = pr;
  }
  __syncthreads();
  {
    float r = ((const float*)&part[0][oq])[oc] + ((const float*)&part[1][oq])[oc]
            + ((const float*)&part[2][oq])[oc] + ((const float*)&part[3][oq])[oc];
    fgs[t] = sigmoid_f(r + fg_b[t]);
  }
  __syncthreads();
  // bp1: K=1024, wave range 256
  {
    float a0 = 0.f, a1 = 0.f, a2 = 0.f, a3 = 0.f;
    int k0 = w * 256;
    #pragma unroll 4
    for (int k = k0; k < k0 + 256; ++k) {
      float b = bv[k];
      float4 a = *(const float4*)(At1 + (size_t)k * 256 + ln * 4);
      a0 += a.x * b; a1 += a.y * b; a2 += a.z * b; a3 += a.w * b;
    }
    float4 pr; pr.x = a0; pr.y = a1; pr.z = a2; pr.w = a3;
    part[w][ln] = pr;
  }
  __syncthreads();
  {
    float r = ((const float*)&part[0][oq])[oc] + ((const float*)&part[1][oq])[oc]
            + ((const float*)&part[2][oq])[oc] + ((const float*)&part[3][oq])[oc];
    hs[t] = gelu_f(r * sc1[t] + bi1[t]);
  }
  __syncthreads();
  // bp2: K=256 over hs, wave range 64
  {
    float a0 = 0.f, a1 = 0.f, a2 = 0.f, a3 = 0.f;
    int k0 = w * 64;
    #pragma unroll 4
    for (int k = k0; k < k0 + 64; ++k) {
      float b = hs[k];
      float4 a = *(const float4*)(At2 + (size_t)k * 256 + ln * 4);
      a0 += a.x * b; a1 += a.y * b; a2 += a.z * b; a3 += a.w * b;
    }
    float4 pr; pr.x = a0; pr.y = a1; pr.z = a2; pr.w = a3;
    part[w][ln] = pr;
  }
  __syncthreads();
  {
    float r = ((const float*)&part[0][oq])[oc] + ((const float*)&part[1][oq])[oc]
            + ((const float*)&part[2][oq])[oc] + ((const float*)&part[3][oq])[oc];
    delta_t[idx] = r * fgs[t] * rs[t];
  }
}

// ---------------- pass 2: out = x + delta * sgate ----------------
__global__ __launch_bounds__(256) void final_kernel(
    const float* __restrict__ x, const float* __restrict__ delta_t,
    const float* __restrict__ sgate_t, float* __restrict__ out) {
  int nc = blockIdx.x; int n = nc >> 8; int c = nc & 255;
  int t = threadIdx.x;
  __shared__ float dlt[64];
  __shared__ float4 sgs4[64];
  if (t < 64) dlt[t] = delta_t[((size_t)n * 64 + t) * 256 + c];
  ((float*)sgs4)[t] = sgate_t[((size_t)n * 256 + t) * 256 + c];
  __syncthreads();
  const float4* x4 = (const float4*)x + (size_t)nc * 4096;
  float4* o4 = (float4*)out + (size_t)nc * 4096;
  int w = t >> 6, l = t & 63;
  float4 sg = sgs4[l];
  for (int i = 0; i < 16; ++i) {
    int s = w * 16 + i;
    float d = dlt[s];
    float4 v = x4[(size_t)s * 64 + l];
    v.x += d * sg.x; v.y += d * sg.y; v.z += d * sg.z; v.w += d * sg.w;
    o4[(size_t)s * 64 + l] = v;
  }
}

} // namespace

extern "C" void kernel_launch(void* const* d_in, const int* in_sizes, int n_in,
                              void* d_out, int out_size, void* d_ws, size_t ws_size,
                              hipStream_t stream) {
  const float* x      = (const float*)d_in[0];
  const float* ln_g   = (const float*)d_in[1];
  const float* ln_b   = (const float*)d_in[2];
  const float* mb_w3  = (const float*)d_in[3];
  const float* mb_s3  = (const float*)d_in[4];
  const float* mb_b3  = (const float*)d_in[5];
  const float* mb_w5  = (const float*)d_in[6];
  const float* mb_s5  = (const float*)d_in[7];
  const float* mb_b5  = (const float*)d_in[8];
  const float* mb_w7  = (const float*)d_in[9];
  const float* mb_s7  = (const float*)d_in[10];
  const float* mb_b7  = (const float*)d_in[11];
  const float* mf_w   = (const float*)d_in[12];
  const float* mf_s   = (const float*)d_in[13];
  const float* mf_b   = (const float*)d_in[14];
  const float* pg_w1  = (const float*)d_in[15];
  const float* pg_s1  = (const float*)d_in[16];
  const float* pg_b1  = (const float*)d_in[17];
  const float* pg_w2  = (const float*)d_in[18];
  const float* pg_b2  = (const float*)d_in[19];
  const float* pp_w   = (const float*)d_in[20];
  const float* pp_s   = (const float*)d_in[21];
  const float* pp_b   = (const float*)d_in[22];
  const float* mg_w   = (const float*)d_in[23];
  const float* mg_b   = (const float*)d_in[24];
  const float* mo_w1  = (const float*)d_in[25];
  const float* mo_s1  = (const float*)d_in[26];
  const float* mo_b1  = (const float*)d_in[27];
  const float* mo_w2  = (const float*)d_in[28];
  const float* rt_w1  = (const float*)d_in[29];
  const float* rt_b1  = (const float*)d_in[30];
  const float* rt_w2  = (const float*)d_in[31];
  const float* rt_b2  = (const float*)d_in[32];
  const float* bp_w1  = (const float*)d_in[33];
  const float* bp_s1  = (const float*)d_in[34];
  const float* bp_b1  = (const float*)d_in[35];
  const float* bp_w2  = (const float*)d_in[36];
  const float* res_sc = (const float*)d_in[37];
  const float* fg_w   = (const float*)d_in[38];
  const float* fg_b   = (const float*)d_in[39];
  const float* sg_w   = (const float*)d_in[40];
  const float* sg_s   = (const float*)d_in[41];
  const float* sg_b   = (const float*)d_in[42];
  float* ws = (float*)d_ws;
  float* out = (float*)d_out;
  unsigned short* wfrag = (unsigned short*)(ws + O_WFRAG);
  unsigned short* im2   = (unsigned short*)(ws + O_IM2);

  weights_kernel<<<2976, 256, 0, stream>>>(mf_w, mg_w, mo_w1, mo_w2, pp_w, bp_w1,
      bp_w2, fg_w, sg_w, ws, mb_w3, mb_w5, mb_w7, wfrag);
  reduce_x_kernel<<<2048, 256, 0, stream>>>(x, ws + O_DESC, ws + O_SPT);
  ln_kernel<<<512, 256, 0, stream>>>(ws + O_DESC, ln_g, ln_b, ws + O_DN);
  post_ln_kernel<<<1736, 256, 0, stream>>>(ws + O_DN, ws + O_ATMG, mg_b, ws + O_GATE,
      im2, ws + O_FE, ws + O_MFRE, ws + O_MFIM);
  conv_scan_kernel<<<400, 256, 0, stream>>>(wfrag, im2, ws + O_CONVC,
      ws + O_DN, ws + O_GATE, ws + O_SCN);
  mid_kernel<<<896, 256, 0, stream>>>(ws + O_CONVC, mb_s3, mb_b3, mb_s5, mb_b5,
      mb_s7, mb_b7, ws + O_ATMF, mf_s, mf_b, ws + O_MOT,
      ws + O_DN, ws + O_SCN, ws + O_ATMO1, mo_s1, mo_b1, ws + O_ATMO2, ws + O_MEM,
      ws + O_FE, ws + O_MFRE, ws + O_MFIM,
      pg_w1, pg_s1, pg_b1, pg_w2, pg_b2, ws + O_ATPP, pp_s, pp_b, ws + O_PHASE,
      ws + O_ATSG, ws + O_SPT, sg_s, sg_b, ws + O_SGATE);
  router_kernel<<<8, 256, 0, stream>>>(ws + O_DN, ws + O_MOT, ws + O_MEM,
      ws + O_FE, ws + O_MFRE, ws + O_MFIM, rt_w1, rt_b1, rt_w2, rt_b2, ws + O_BW);
  delta_kernel<<<512, 256, 0, stream>>>(ws + O_DN, ws + O_MOT, ws + O_PHASE, ws + O_MEM,
      ws + O_BW, ws + O_ATFG, fg_b, ws + O_ATBP1, bp_s1, bp_b1, ws + O_ATBP2, res_sc,
      ws + O_DELTA);
  final_kernel<<<2048, 256, 0, stream>>>(x, ws + O_DELTA, ws + O_SGATE, out);
}